// Round 23
// baseline (1011.739 us; speedup 1.0000x reference)
//
#include <hip/hip_runtime.h>
#include <cstdint>

using u16 = unsigned short;
using u32 = unsigned int;

typedef __bf16 bf16x8 __attribute__((ext_vector_type(8)));
typedef float f32x4 __attribute__((ext_vector_type(4)));

__device__ __forceinline__ float bf2f(u16 u) {
    u32 v = ((u32)u) << 16; float f; __builtin_memcpy(&f, &v, 4); return f;
}
__device__ __forceinline__ u16 f2bf(float f) {
    u32 u; __builtin_memcpy(&u, &f, 4);
    u32 r = (u + 0x7fffu + ((u >> 16) & 1u)) >> 16; return (u16)r;
}
__device__ __forceinline__ u32 pack2(float a, float b) {
    return (u32)f2bf(a) | ((u32)f2bf(b) << 16);
}
// bijective chunked XCD swizzle (m204)
__device__ __forceinline__ int xcd_swz(int orig, int nwg) {
    int q = nwg >> 3, r8 = nwg & 7;
    int xcd = orig & 7, slot = orig >> 3;
    return (xcd < r8 ? xcd * (q + 1) : r8 * (q + 1) + (xcd - r8) * q) + slot;
}
// async global->LDS, 16B/lane; LDS dest wave-uniform base + lane*16
__device__ __forceinline__ void async_cp16(const u16* g, u16* l) {
    __builtin_amdgcn_global_load_lds(
        (const __attribute__((address_space(1))) void*)g,
        (__attribute__((address_space(3))) void*)l, 16, 0, 0);
}

// ---------------------------------------------------------------------------
// weight transpose: w [R][C] fp32 -> wt [C][R] bf16
// ---------------------------------------------------------------------------
__global__ __launch_bounds__(256) void transp_k(const float* __restrict__ in,
                                                u16* __restrict__ outp,
                                                int R, int C) {
    __shared__ alignas(16) u16 t[32][33];
    int tx = threadIdx.x & 31, ty = threadIdx.x >> 5;
    int bx = blockIdx.x * 32, by = blockIdx.y * 32;
#pragma unroll
    for (int i = 0; i < 4; ++i)
        t[ty + i * 8][tx] = f2bf(in[(size_t)(by + ty + i * 8) * C + bx + tx]);
    __syncthreads();
#pragma unroll
    for (int i = 0; i < 4; ++i)
        outp[(size_t)(bx + ty + i * 8) * R + by + tx] = t[tx][ty + i * 8];
}

// ---------------------------------------------------------------------------
// swb prep: sw [16][49][49] f32 -> swb [16][64][64] bf16, zero-padded
// ---------------------------------------------------------------------------
__global__ __launch_bounds__(256) void swb_k(const float* __restrict__ sw,
                                             u16* __restrict__ swb) {
    int idx = blockIdx.x * 256 + threadIdx.x;       // 65536 total
    int h = idx >> 12, r = (idx >> 6) & 63, j = idx & 63;
    u16 v = 0;
    if (r < 49 && j < 49) v = f2bf(sw[(size_t)h * 2401 + r * 49 + j]);
    swb[idx] = v;
}

// ---------------------------------------------------------------------------
// Fused LN1 + MFMA window mix + LN2 (unchanged from round-22 pass)
// ---------------------------------------------------------------------------
__global__ __launch_bounds__(512) void spatial_k(const float* __restrict__ xin,
                                                 const float* __restrict__ g1,
                                                 const float* __restrict__ b1,
                                                 const u16* __restrict__ swb,
                                                 const float* __restrict__ sb,
                                                 const float* __restrict__ g2,
                                                 const float* __restrict__ b2,
                                                 u16* __restrict__ xmid,
                                                 u16* __restrict__ ln2o) {
    __shared__ alignas(16) char poolc[123904];       // raw(50176) | lnT(73728) ; oL union
    __shared__ float sbl[784];
    __shared__ int toks[49];
    u16* raw = (u16*)poolc;                          // [49][512] bf16
    u16* lnT = (u16*)(poolc + 50176);                // [512][72] bf16
    float* oL = (float*)poolc;                       // [49][520] f32 (after M)
    const int tid = threadIdx.x;
    const int wid = blockIdx.x;
    const int b = wid / 81, rem = wid % 81;
    const int wy = rem / 9, wx = rem % 9;

    if (tid < 49) {
        int py = tid / 7, px = tid % 7;
        int y = wy * 7 + py - 4, x = wx * 7 + px - 4;  // PT=PL=4
        toks[tid] = ((unsigned)y < 56u && (unsigned)x < 56u)
                        ? (b * 3136 + y * 56 + x) : -1;
    }
    for (int idx = tid; idx < 784; idx += 512) sbl[idx] = sb[idx];
    __syncthreads();

    const int l = tid & 63, wvi = tid >> 6;
    const int lr = l & 15, lk = l >> 4;

    // ---- phase A: LN1 per position (one wave per position, stride 8)
    {
        float g1v[8], b1v[8];
#pragma unroll
        for (int j = 0; j < 8; ++j) { g1v[j] = g1[l * 8 + j]; b1v[j] = b1[l * 8 + j]; }
        for (int p = wvi; p < 49; p += 8) {
            int tk = toks[p];
            uint4 w = make_uint4(0, 0, 0, 0);
            if (tk >= 0) {
                const float4* pp = (const float4*)(xin + (size_t)tk * 512 + l * 8);
                float4 a = pp[0], bb = pp[1];
                float v[8] = {a.x, a.y, a.z, a.w, bb.x, bb.y, bb.z, bb.w};
                float s = 0.f, qq = 0.f;
#pragma unroll
                for (int j = 0; j < 8; ++j) { s += v[j]; qq += v[j] * v[j]; }
#pragma unroll
                for (int off = 1; off < 64; off <<= 1) {
                    s += __shfl_xor(s, off); qq += __shfl_xor(qq, off);
                }
                float m = s * (1.f / 512.f);
                float var = qq * (1.f / 512.f) - m * m;
                float r = rsqrtf(var + 1e-5f);
                float o[8];
#pragma unroll
                for (int j = 0; j < 8; ++j)
                    o[j] = (v[j] - m) * r * g1v[j] + b1v[j];
                w.x = pack2(o[0], o[1]); w.y = pack2(o[2], o[3]);
                w.z = pack2(o[4], o[5]); w.w = pack2(o[6], o[7]);
            }
            *(uint4*)(raw + p * 512 + l * 8) = w;
        }
    }
    __syncthreads();

    // ---- phase T: transpose raw[j][c] -> lnT[c][j] (chunk-XOR, zero pad)
    {
        const int c = tid;
#pragma unroll
        for (int m = 0; m < 8; ++m) {
            u32 d[4];
#pragma unroll
            for (int e2 = 0; e2 < 4; ++e2) {
                int j0 = m * 8 + e2 * 2, j1 = j0 + 1;
                u16 v0 = (j0 < 49) ? raw[j0 * 512 + c] : (u16)0;
                u16 v1 = (j1 < 49) ? raw[j1 * 512 + c] : (u16)0;
                d[e2] = (u32)v0 | ((u32)v1 << 16);
            }
            uint4 w = make_uint4(d[0], d[1], d[2], d[3]);
            *(uint4*)(lnT + c * 72 + ((m ^ (c & 7)) * 8)) = w;
        }
    }
    __syncthreads();

    // ---- phase M: per wave heads {2*wvi, 2*wvi+1}; 16 MFMA per head
    f32x4 acc[2][4][2] = {};   // [hh][tp][tn]
#pragma unroll
    for (int hh = 0; hh < 2; ++hh) {
        const int h = wvi * 2 + hh;
        bf16x8 bfr[2][2];      // [tn][kk]
#pragma unroll
        for (int tn = 0; tn < 2; ++tn)
#pragma unroll
            for (int kk = 0; kk < 2; ++kk) {
                int crow = h * 32 + tn * 16 + lr;
                bfr[tn][kk] = *reinterpret_cast<const bf16x8*>(
                    lnT + crow * 72 + (((kk * 4 + lk) ^ (crow & 7)) * 8));
            }
        bf16x8 af[4][2];       // [tp][kk]
#pragma unroll
        for (int tp = 0; tp < 4; ++tp)
#pragma unroll
            for (int kk = 0; kk < 2; ++kk)
                af[tp][kk] = *reinterpret_cast<const bf16x8*>(
                    swb + h * 4096 + (tp * 16 + lr) * 64 + (kk * 4 + lk) * 8);
#pragma unroll
        for (int tp = 0; tp < 4; ++tp)
#pragma unroll
            for (int tn = 0; tn < 2; ++tn)
#pragma unroll
                for (int kk = 0; kk < 2; ++kk)
                    acc[hh][tp][tn] = __builtin_amdgcn_mfma_f32_16x16x32_bf16(
                        af[tp][kk], bfr[tn][kk], acc[hh][tp][tn], 0, 0, 0);
    }
    __syncthreads();   // all lnT reads retired before oL overwrites the union

    // ---- phase S: stage acc + sb into oL[p][520]
#pragma unroll
    for (int hh = 0; hh < 2; ++hh) {
        const int h = wvi * 2 + hh;
#pragma unroll
        for (int tp = 0; tp < 4; ++tp)
#pragma unroll
            for (int tn = 0; tn < 2; ++tn)
#pragma unroll
                for (int rg = 0; rg < 4; ++rg) {
                    int p = tp * 16 + lk * 4 + rg;
                    if (p < 49) {
                        int c = h * 32 + tn * 16 + lr;
                        oL[p * 520 + c] = acc[hh][tp][tn][rg] + sbl[h * 49 + p];
                    }
                }
    }
    __syncthreads();

    // ---- phase F: row-major finalize (one wave per position, stride 8)
    {
        float g2v[8], b2v[8];
#pragma unroll
        for (int j = 0; j < 8; ++j) { g2v[j] = g2[l * 8 + j]; b2v[j] = b2[l * 8 + j]; }
        for (int p = wvi; p < 49; p += 8) {
            int tk = toks[p];
            if (tk < 0) continue;
            const float* orow = oL + p * 520 + l * 8;
            float4 oa = *(const float4*)orow;
            float4 ob = *(const float4*)(orow + 4);
            const float4* xp4 = (const float4*)(xin + (size_t)tk * 512 + l * 8);
            float4 xa = xp4[0], xb = xp4[1];
            float o[8] = {oa.x + xa.x, oa.y + xa.y, oa.z + xa.z, oa.w + xa.w,
                          ob.x + xb.x, ob.y + xb.y, ob.z + xb.z, ob.w + xb.w};
            float s = 0.f, qq = 0.f;
#pragma unroll
            for (int j = 0; j < 8; ++j) { s += o[j]; qq += o[j] * o[j]; }
#pragma unroll
            for (int off = 1; off < 64; off <<= 1) {
                s += __shfl_xor(s, off); qq += __shfl_xor(qq, off);
            }
            float m = s * (1.f / 512.f);
            float var = qq * (1.f / 512.f) - m * m;
            float r = rsqrtf(var + 1e-5f);
            uint4 wx_, wl_;
            wx_.x = pack2(o[0], o[1]); wx_.y = pack2(o[2], o[3]);
            wx_.z = pack2(o[4], o[5]); wx_.w = pack2(o[6], o[7]);
            float ln[8];
#pragma unroll
            for (int j = 0; j < 8; ++j)
                ln[j] = (o[j] - m) * r * g2v[j] + b2v[j];
            wl_.x = pack2(ln[0], ln[1]); wl_.y = pack2(ln[2], ln[3]);
            wl_.z = pack2(ln[4], ln[5]); wl_.w = pack2(ln[6], ln[7]);
            *(uint4*)(xmid + (size_t)tk * 512 + l * 8) = wx_;
            *(uint4*)(ln2o + (size_t)tk * 512 + l * 8) = wl_;
        }
    }
}

// ---------------------------------------------------------------------------
// MFMA GEMM, SINGLE-buffered 256x256 tile, 8 waves (2m x 4n), BK=64,
// gload_lds staging into 64 KB LDS -> 2 blocks/CU (16 waves): cross-block
// wave overlap (m114) hides the per-K-step stage+drain that the 1-block/CU
// double-buffered variant could not. XCD-swizzled 1D grid.
// EPI==0: bias + fast tanh-GELU -> Out bf16 (chunk-local rows)
// EPI==1: four-phase 64x256 f32 LDS C-tile + WRITE-ONLY f32 out:
//         out = bf16(xmid) + (acc+bias)
// ---------------------------------------------------------------------------
template <int KD, int ND, int EPI>
__global__ __launch_bounds__(512) void gemm_k(const u16* __restrict__ A,
                                              const u16* __restrict__ Wt,
                                              const float* __restrict__ bias,
                                              const u16* __restrict__ Xm,
                                              void* __restrict__ Out, int row0) {
    __shared__ alignas(16) u16 smem[32768];   // A(16K u16) | B(16K u16) = 64 KB
    const int tid = threadIdx.x;
    const int l = tid & 63, wid = tid >> 6;
    const int wm = wid >> 2, wn = wid & 3;
    const int lr = l & 15, lk = l >> 4;

    const int wg = xcd_swz(blockIdx.x, gridDim.x);
    constexpr int NTN = ND / 256;
    const int bm = wg / NTN, bn = wg % NTN;   // consecutive wg share bm

    // staging: physical slot s holds logical chunk pc^(rr&7); 4 A + 4 B per thread
    const u16* gA[4]; const u16* gB[4];
    int lofs[4];
#pragma unroll
    for (int i = 0; i < 4; ++i) {
        int s = (wid * 4 + i) * 64 + l;            // [0, 2048)
        int rr = s >> 3, pc = s & 7, cc = pc ^ (rr & 7);
        gA[i] = A  + (size_t)(bm * 256 + rr) * KD + cc * 8;
        gB[i] = Wt + (size_t)(bn * 256 + rr) * KD + cc * 8;
        lofs[i] = (wid * 4 + i) * 512;             // element offset, wave-uniform
    }

    f32x4 acc[8][4] = {};

    for (int ks = 0; ks < KD; ks += 64) {
        // stage tile ks (cross-block overlap hides issue+latency)
#pragma unroll
        for (int i = 0; i < 4; ++i) async_cp16(gA[i], smem + lofs[i]);
#pragma unroll
        for (int i = 0; i < 4; ++i) async_cp16(gB[i], smem + 16384 + lofs[i]);
#pragma unroll
        for (int i = 0; i < 4; ++i) { gA[i] += 64; gB[i] += 64; }
        asm volatile("s_waitcnt vmcnt(0)" ::: "memory");
        __syncthreads();
        const u16* As = smem;
        const u16* Bs = smem + 16384;
#pragma unroll
        for (int kk = 0; kk < 2; ++kk) {
            bf16x8 af[8], bfr[4];
#pragma unroll
            for (int f = 0; f < 8; ++f) {
                int ra = wm * 128 + f * 16 + lr;
                af[f] = *reinterpret_cast<const bf16x8*>(
                    As + ra * 64 + (((kk * 4 + lk) ^ (ra & 7)) * 8));
            }
#pragma unroll
            for (int f = 0; f < 4; ++f) {
                int rb = wn * 64 + f * 16 + lr;
                bfr[f] = *reinterpret_cast<const bf16x8*>(
                    Bs + rb * 64 + (((kk * 4 + lk) ^ (rb & 7)) * 8));
            }
#pragma unroll
            for (int fi = 0; fi < 8; ++fi)
#pragma unroll
                for (int fj = 0; fj < 4; ++fj)
                    acc[fi][fj] = __builtin_amdgcn_mfma_f32_16x16x32_bf16(
                        af[fi], bfr[fj], acc[fi][fj], 0, 0, 0);
        }
        __syncthreads();   // all reads retired before next stage overwrites
    }

    if (EPI == 0) {
        // bias + fast tanh-GELU -> bf16 Out. D row=(lane>>4)*4+reg, col=lane&15
        u16* O16 = (u16*)Out;
#pragma unroll
        for (int fi = 0; fi < 8; ++fi) {
#pragma unroll
            for (int fj = 0; fj < 4; ++fj) {
#pragma unroll
                for (int rr = 0; rr < 4; ++rr) {
                    int mrow = bm * 256 + wm * 128 + fi * 16 + lk * 4 + rr;
                    int ncol = bn * 256 + wn * 64 + fj * 16 + lr;
                    float v = acc[fi][fj][rr] + bias[ncol];
                    float u_ = v * (0.7978845608028654f + 0.03567740813636141f * v * v);
                    float ge = v / (1.f + __expf(-2.f * u_));
                    O16[(size_t)mrow * ND + ncol] = f2bf(ge);
                }
            }
        }
    } else {
        // four-phase (rows q*64..q*64+63): 64x256 f32 LDS C-tile (64 KB),
        // then WRITE-ONLY f32 out = bf16(xmid) + c  (dense float4 stores)
        float* Of = (float*)Out;
        float* Cs = (float*)smem;
#pragma unroll
        for (int q = 0; q < 4; ++q) {
            if (wm == (q >> 1)) {
                const int f0 = (q & 1) * 4;
#pragma unroll
                for (int fi = 0; fi < 4; ++fi) {
#pragma unroll
                    for (int fj = 0; fj < 4; ++fj) {
                        int col = wn * 64 + fj * 16 + lr;
                        float bcol = bias[bn * 256 + col];
#pragma unroll
                        for (int rr = 0; rr < 4; ++rr) {
                            int row = fi * 16 + lk * 4 + rr;   // 0..63
                            Cs[row * 256 + col] = acc[f0 + fi][fj][rr] + bcol;
                        }
                    }
                }
            }
            __syncthreads();
#pragma unroll
            for (int it = 0; it < 4; ++it) {
                int row = it * 16 + (tid >> 5);
                int cf = (tid & 31) * 8;
                float4 c0 = *(const float4*)(Cs + row * 256 + cf);
                float4 c1 = *(const float4*)(Cs + row * 256 + cf + 4);
                size_t go = (size_t)(row0 + bm * 256 + q * 64 + row) * ND
                            + bn * 256 + cf;
                uint4 xm = *(const uint4*)(Xm + go);
                const u16* xp = (const u16*)&xm;
                float4 r0, r1;
                r0.x = bf2f(xp[0]) + c0.x; r0.y = bf2f(xp[1]) + c0.y;
                r0.z = bf2f(xp[2]) + c0.z; r0.w = bf2f(xp[3]) + c0.w;
                r1.x = bf2f(xp[4]) + c1.x; r1.y = bf2f(xp[5]) + c1.y;
                r1.z = bf2f(xp[6]) + c1.z; r1.w = bf2f(xp[7]) + c1.w;
                *(float4*)(Of + go) = r0;
                *(float4*)(Of + go + 4) = r1;
            }
            __syncthreads();
        }
    }
}

// ---------------------------------------------------------------------------
extern "C" void kernel_launch(void* const* d_in, const int* in_sizes, int n_in,
                              void* d_out, int out_size, void* d_ws, size_t ws_size,
                              hipStream_t stream) {
    const float* x   = (const float*)d_in[0];
    const float* g1  = (const float*)d_in[1];
    const float* b1  = (const float*)d_in[2];
    const float* sw  = (const float*)d_in[3];
    const float* sb  = (const float*)d_in[4];
    const float* g2  = (const float*)d_in[5];
    const float* b2  = (const float*)d_in[6];
    const float* w1  = (const float*)d_in[7];
    const float* bb1 = (const float*)d_in[8];
    const float* w2  = (const float*)d_in[9];
    const float* bb2 = (const float*)d_in[10];
    float* out = (float*)d_out;

    char* ws = (char*)d_ws;
    u16* w1t = (u16*)ws;                                  // [2048][512]  2 MB
    u16* w2t = (u16*)(ws + 2097152);                      // [512][2048]  2 MB
    u16* swb = (u16*)(ws + 2u * 2097152);                 // [16][64][64] 128 KB
    size_t tok_bytes = (size_t)100352 * 512 * 2;          // 102.8 MB each
    u16* ln2c = (u16*)(ws + 2u * 2097152 + 131072);
    u16* xmid = (u16*)(ws + 2u * 2097152 + 131072 + tok_bytes);
    size_t hidoff = 2u * 2097152 + 131072 + 2u * tok_bytes;
    long avail = (long)ws_size - (long)hidoff;
    long maxT = avail / 524288;                           // hid per 128 rows
    int chunkT = (int)(maxT < 2 ? 2 : (maxT > 784 ? 784 : maxT));
    chunkT &= ~1;                                          // 256-row tiles
    u16* hid = (u16*)(ws + hidoff);

    transp_k<<<dim3(64, 16), 256, 0, stream>>>(w1, w1t, 512, 2048);
    transp_k<<<dim3(16, 64), 256, 0, stream>>>(w2, w2t, 2048, 512);
    swb_k<<<256, 256, 0, stream>>>(sw, swb);
    spatial_k<<<2592, 512, 0, stream>>>(x, g1, b1, swb, sb, g2, b2, xmid, ln2c);
    for (int t0 = 0; t0 < 784; t0 += chunkT) {
        int nt = (784 - t0) < chunkT ? (784 - t0) : chunkT;
        int nt2 = nt >> 1;                                 // 256-row tiles
        gemm_k<512, 2048, 0><<<nt2 * 8, 512, 0, stream>>>(
            ln2c + (size_t)t0 * 128 * 512, w1t, bb1, nullptr, hid, 0);
        gemm_k<2048, 512, 1><<<nt2 * 2, 512, 0, stream>>>(
            hid, w2t, bb2, xmid, out, t0 * 128);
    }
}

// Round 24
// 856.403 us; speedup vs baseline: 1.1814x; 1.1814x over previous
//
#include <hip/hip_runtime.h>
#include <cstdint>

using u16 = unsigned short;
using u32 = unsigned int;

typedef __bf16 bf16x8 __attribute__((ext_vector_type(8)));
typedef float f32x4 __attribute__((ext_vector_type(4)));

__device__ __forceinline__ float bf2f(u16 u) {
    u32 v = ((u32)u) << 16; float f; __builtin_memcpy(&f, &v, 4); return f;
}
__device__ __forceinline__ u16 f2bf(float f) {
    u32 u; __builtin_memcpy(&u, &f, 4);
    u32 r = (u + 0x7fffu + ((u >> 16) & 1u)) >> 16; return (u16)r;
}
__device__ __forceinline__ u32 pack2(float a, float b) {
    return (u32)f2bf(a) | ((u32)f2bf(b) << 16);
}
// bijective chunked XCD swizzle (m204)
__device__ __forceinline__ int xcd_swz(int orig, int nwg) {
    int q = nwg >> 3, r8 = nwg & 7;
    int xcd = orig & 7, slot = orig >> 3;
    return (xcd < r8 ? xcd * (q + 1) : r8 * (q + 1) + (xcd - r8) * q) + slot;
}
// async global->LDS, 16B/lane; LDS dest wave-uniform base + lane*16
__device__ __forceinline__ void async_cp16(const u16* g, u16* l) {
    __builtin_amdgcn_global_load_lds(
        (const __attribute__((address_space(1))) void*)g,
        (__attribute__((address_space(3))) void*)l, 16, 0, 0);
}

// ---------------------------------------------------------------------------
// weight transpose: w [R][C] fp32 -> wt [C][R] bf16
// ---------------------------------------------------------------------------
__global__ __launch_bounds__(256) void transp_k(const float* __restrict__ in,
                                                u16* __restrict__ outp,
                                                int R, int C) {
    __shared__ alignas(16) u16 t[32][33];
    int tx = threadIdx.x & 31, ty = threadIdx.x >> 5;
    int bx = blockIdx.x * 32, by = blockIdx.y * 32;
#pragma unroll
    for (int i = 0; i < 4; ++i)
        t[ty + i * 8][tx] = f2bf(in[(size_t)(by + ty + i * 8) * C + bx + tx]);
    __syncthreads();
#pragma unroll
    for (int i = 0; i < 4; ++i)
        outp[(size_t)(bx + ty + i * 8) * R + by + tx] = t[tx][ty + i * 8];
}

// ---------------------------------------------------------------------------
// swb prep: sw [16][49][49] f32 -> swb [16][64][64] bf16, zero-padded
// ---------------------------------------------------------------------------
__global__ __launch_bounds__(256) void swb_k(const float* __restrict__ sw,
                                             u16* __restrict__ swb) {
    int idx = blockIdx.x * 256 + threadIdx.x;       // 65536 total
    int h = idx >> 12, r = (idx >> 6) & 63, j = idx & 63;
    u16 v = 0;
    if (r < 49 && j < 49) v = f2bf(sw[(size_t)h * 2401 + r * 49 + j]);
    swb[idx] = v;
}

// ---------------------------------------------------------------------------
// Fused LN1 + MFMA window mix + LN2.
//   A: LN1 -> raw[j][c] bf16 (zeros at pads)
//   T: transpose raw -> lnT[c][72] (chunk-XOR m^(c&7), K-pad 64)
//   M: per wave 2 heads; OUT_h = SW_h @ LN_h via 16x16x32 MFMA
//   S: stage acc+sb -> oL[49][520] f32 (LDS union over raw+lnT)
//   F: row-major finalize: o = oL + x (dense float4), 64-lane LN2 reduce,
//      packed uint4 writes of xmid bf16 + ln2(o)*g2+b2 bf16
// ---------------------------------------------------------------------------
__global__ __launch_bounds__(512) void spatial_k(const float* __restrict__ xin,
                                                 const float* __restrict__ g1,
                                                 const float* __restrict__ b1,
                                                 const u16* __restrict__ swb,
                                                 const float* __restrict__ sb,
                                                 const float* __restrict__ g2,
                                                 const float* __restrict__ b2,
                                                 u16* __restrict__ xmid,
                                                 u16* __restrict__ ln2o) {
    __shared__ alignas(16) char poolc[123904];       // raw(50176) | lnT(73728) ; oL union
    __shared__ float sbl[784];
    __shared__ int toks[49];
    u16* raw = (u16*)poolc;                          // [49][512] bf16
    u16* lnT = (u16*)(poolc + 50176);                // [512][72] bf16
    float* oL = (float*)poolc;                       // [49][520] f32 (after M)
    const int tid = threadIdx.x;
    const int wid = blockIdx.x;
    const int b = wid / 81, rem = wid % 81;
    const int wy = rem / 9, wx = rem % 9;

    if (tid < 49) {
        int py = tid / 7, px = tid % 7;
        int y = wy * 7 + py - 4, x = wx * 7 + px - 4;  // PT=PL=4
        toks[tid] = ((unsigned)y < 56u && (unsigned)x < 56u)
                        ? (b * 3136 + y * 56 + x) : -1;
    }
    for (int idx = tid; idx < 784; idx += 512) sbl[idx] = sb[idx];
    __syncthreads();

    const int l = tid & 63, wvi = tid >> 6;
    const int lr = l & 15, lk = l >> 4;

    // ---- phase A: LN1 per position (one wave per position, stride 8)
    {
        float g1v[8], b1v[8];
#pragma unroll
        for (int j = 0; j < 8; ++j) { g1v[j] = g1[l * 8 + j]; b1v[j] = b1[l * 8 + j]; }
        for (int p = wvi; p < 49; p += 8) {
            int tk = toks[p];
            uint4 w = make_uint4(0, 0, 0, 0);
            if (tk >= 0) {
                const float4* pp = (const float4*)(xin + (size_t)tk * 512 + l * 8);
                float4 a = pp[0], bb = pp[1];
                float v[8] = {a.x, a.y, a.z, a.w, bb.x, bb.y, bb.z, bb.w};
                float s = 0.f, qq = 0.f;
#pragma unroll
                for (int j = 0; j < 8; ++j) { s += v[j]; qq += v[j] * v[j]; }
#pragma unroll
                for (int off = 1; off < 64; off <<= 1) {
                    s += __shfl_xor(s, off); qq += __shfl_xor(qq, off);
                }
                float m = s * (1.f / 512.f);
                float var = qq * (1.f / 512.f) - m * m;
                float r = rsqrtf(var + 1e-5f);
                float o[8];
#pragma unroll
                for (int j = 0; j < 8; ++j)
                    o[j] = (v[j] - m) * r * g1v[j] + b1v[j];
                w.x = pack2(o[0], o[1]); w.y = pack2(o[2], o[3]);
                w.z = pack2(o[4], o[5]); w.w = pack2(o[6], o[7]);
            }
            *(uint4*)(raw + p * 512 + l * 8) = w;
        }
    }
    __syncthreads();

    // ---- phase T: transpose raw[j][c] -> lnT[c][j] (chunk-XOR, zero pad)
    {
        const int c = tid;
#pragma unroll
        for (int m = 0; m < 8; ++m) {
            u32 d[4];
#pragma unroll
            for (int e2 = 0; e2 < 4; ++e2) {
                int j0 = m * 8 + e2 * 2, j1 = j0 + 1;
                u16 v0 = (j0 < 49) ? raw[j0 * 512 + c] : (u16)0;
                u16 v1 = (j1 < 49) ? raw[j1 * 512 + c] : (u16)0;
                d[e2] = (u32)v0 | ((u32)v1 << 16);
            }
            uint4 w = make_uint4(d[0], d[1], d[2], d[3]);
            *(uint4*)(lnT + c * 72 + ((m ^ (c & 7)) * 8)) = w;
        }
    }
    __syncthreads();

    // ---- phase M: per wave heads {2*wvi, 2*wvi+1}; 16 MFMA per head
    f32x4 acc[2][4][2] = {};   // [hh][tp][tn]
#pragma unroll
    for (int hh = 0; hh < 2; ++hh) {
        const int h = wvi * 2 + hh;
        bf16x8 bfr[2][2];      // [tn][kk]
#pragma unroll
        for (int tn = 0; tn < 2; ++tn)
#pragma unroll
            for (int kk = 0; kk < 2; ++kk) {
                int crow = h * 32 + tn * 16 + lr;
                bfr[tn][kk] = *reinterpret_cast<const bf16x8*>(
                    lnT + crow * 72 + (((kk * 4 + lk) ^ (crow & 7)) * 8));
            }
        bf16x8 af[4][2];       // [tp][kk]
#pragma unroll
        for (int tp = 0; tp < 4; ++tp)
#pragma unroll
            for (int kk = 0; kk < 2; ++kk)
                af[tp][kk] = *reinterpret_cast<const bf16x8*>(
                    swb + h * 4096 + (tp * 16 + lr) * 64 + (kk * 4 + lk) * 8);
#pragma unroll
        for (int tp = 0; tp < 4; ++tp)
#pragma unroll
            for (int tn = 0; tn < 2; ++tn)
#pragma unroll
                for (int kk = 0; kk < 2; ++kk)
                    acc[hh][tp][tn] = __builtin_amdgcn_mfma_f32_16x16x32_bf16(
                        af[tp][kk], bfr[tn][kk], acc[hh][tp][tn], 0, 0, 0);
    }
    __syncthreads();   // all lnT reads retired before oL overwrites the union

    // ---- phase S: stage acc + sb into oL[p][520]
#pragma unroll
    for (int hh = 0; hh < 2; ++hh) {
        const int h = wvi * 2 + hh;
#pragma unroll
        for (int tp = 0; tp < 4; ++tp)
#pragma unroll
            for (int tn = 0; tn < 2; ++tn)
#pragma unroll
                for (int rg = 0; rg < 4; ++rg) {
                    int p = tp * 16 + lk * 4 + rg;
                    if (p < 49) {
                        int c = h * 32 + tn * 16 + lr;
                        oL[p * 520 + c] = acc[hh][tp][tn][rg] + sbl[h * 49 + p];
                    }
                }
    }
    __syncthreads();

    // ---- phase F: row-major finalize (one wave per position, stride 8)
    {
        float g2v[8], b2v[8];
#pragma unroll
        for (int j = 0; j < 8; ++j) { g2v[j] = g2[l * 8 + j]; b2v[j] = b2[l * 8 + j]; }
        for (int p = wvi; p < 49; p += 8) {
            int tk = toks[p];
            if (tk < 0) continue;
            const float* orow = oL + p * 520 + l * 8;
            float4 oa = *(const float4*)orow;
            float4 ob = *(const float4*)(orow + 4);
            const float4* xp4 = (const float4*)(xin + (size_t)tk * 512 + l * 8);
            float4 xa = xp4[0], xb = xp4[1];
            float o[8] = {oa.x + xa.x, oa.y + xa.y, oa.z + xa.z, oa.w + xa.w,
                          ob.x + xb.x, ob.y + xb.y, ob.z + xb.z, ob.w + xb.w};
            float s = 0.f, qq = 0.f;
#pragma unroll
            for (int j = 0; j < 8; ++j) { s += o[j]; qq += o[j] * o[j]; }
#pragma unroll
            for (int off = 1; off < 64; off <<= 1) {
                s += __shfl_xor(s, off); qq += __shfl_xor(qq, off);
            }
            float m = s * (1.f / 512.f);
            float var = qq * (1.f / 512.f) - m * m;
            float r = rsqrtf(var + 1e-5f);
            uint4 wx_, wl_;
            wx_.x = pack2(o[0], o[1]); wx_.y = pack2(o[2], o[3]);
            wx_.z = pack2(o[4], o[5]); wx_.w = pack2(o[6], o[7]);
            float ln[8];
#pragma unroll
            for (int j = 0; j < 8; ++j)
                ln[j] = (o[j] - m) * r * g2v[j] + b2v[j];
            wl_.x = pack2(ln[0], ln[1]); wl_.y = pack2(ln[2], ln[3]);
            wl_.z = pack2(ln[4], ln[5]); wl_.w = pack2(ln[6], ln[7]);
            *(uint4*)(xmid + (size_t)tk * 512 + l * 8) = wx_;
            *(uint4*)(ln2o + (size_t)tk * 512 + l * 8) = wl_;
        }
    }
}

// ---------------------------------------------------------------------------
// MFMA GEMM (R12-measured variant): 256x256 tile, 8 waves (2m x 4n), BK=64,
// 2-phase double-buffered gload_lds staging (pre-swizzled source chunk
// c^(r&7), linear LDS dest), 128 KB LDS, one vmcnt(0)+barrier per K-step
// AFTER the 512-MFMA block. XCD-swizzled 1D grid.
// EPI==0: bias + fast tanh-GELU -> Out bf16 (chunk-local rows)
// EPI==1: two-phase (by wm) 128x256 f32 LDS C-tile + WRITE-ONLY f32 out:
//         out = bf16(xmid) + (acc+bias)  (no RMW read of f32 d_out)
// ---------------------------------------------------------------------------
template <int KD, int ND, int EPI>
__global__ __launch_bounds__(512) void gemm_k(const u16* __restrict__ A,
                                              const u16* __restrict__ Wt,
                                              const float* __restrict__ bias,
                                              const u16* __restrict__ Xm,
                                              void* __restrict__ Out, int row0) {
    __shared__ alignas(16) u16 smem[2 * 32768];   // [buf][A(16K u16)|B(16K u16)]
    const int tid = threadIdx.x;
    const int l = tid & 63, wid = tid >> 6;
    const int wm = wid >> 2, wn = wid & 3;
    const int lr = l & 15, lk = l >> 4;

    const int wg = xcd_swz(blockIdx.x, gridDim.x);
    constexpr int NTN = ND / 256;
    const int bm = wg / NTN, bn = wg % NTN;   // consecutive wg share bm

    // staging: physical slot s holds logical chunk pc^(rr&7); 4 A + 4 B per thread
    const u16* gA[4]; const u16* gB[4];
    int lofs[4];
#pragma unroll
    for (int i = 0; i < 4; ++i) {
        int s = (wid * 4 + i) * 64 + l;            // [0, 2048)
        int rr = s >> 3, pc = s & 7, cc = pc ^ (rr & 7);
        gA[i] = A  + (size_t)(bm * 256 + rr) * KD + cc * 8;
        gB[i] = Wt + (size_t)(bn * 256 + rr) * KD + cc * 8;
        lofs[i] = (wid * 4 + i) * 512;             // element offset, wave-uniform
    }

    f32x4 acc[8][4] = {};

    // prologue: stage tile 0 into buf 0
#pragma unroll
    for (int i = 0; i < 4; ++i) async_cp16(gA[i], smem + lofs[i]);
#pragma unroll
    for (int i = 0; i < 4; ++i) async_cp16(gB[i], smem + 16384 + lofs[i]);
#pragma unroll
    for (int i = 0; i < 4; ++i) { gA[i] += 64; gB[i] += 64; }
    asm volatile("s_waitcnt vmcnt(0)" ::: "memory");
    __syncthreads();

    int cur = 0;
    for (int ks = 0; ks < KD; ks += 64) {
        // issue next tile's loads into the other buffer (fly under MFMA)
        if (ks + 64 < KD) {
            u16* dst = smem + (cur ^ 1) * 32768;
#pragma unroll
            for (int i = 0; i < 4; ++i) async_cp16(gA[i], dst + lofs[i]);
#pragma unroll
            for (int i = 0; i < 4; ++i) async_cp16(gB[i], dst + 16384 + lofs[i]);
#pragma unroll
            for (int i = 0; i < 4; ++i) { gA[i] += 64; gB[i] += 64; }
        }
        const u16* As = smem + cur * 32768;
        const u16* Bs = As + 16384;
#pragma unroll
        for (int kk = 0; kk < 2; ++kk) {
            bf16x8 af[8], bfr[4];
#pragma unroll
            for (int f = 0; f < 8; ++f) {
                int ra = wm * 128 + f * 16 + lr;
                af[f] = *reinterpret_cast<const bf16x8*>(
                    As + ra * 64 + (((kk * 4 + lk) ^ (ra & 7)) * 8));
            }
#pragma unroll
            for (int f = 0; f < 4; ++f) {
                int rb = wn * 64 + f * 16 + lr;
                bfr[f] = *reinterpret_cast<const bf16x8*>(
                    Bs + rb * 64 + (((kk * 4 + lk) ^ (rb & 7)) * 8));
            }
#pragma unroll
            for (int fi = 0; fi < 8; ++fi)
#pragma unroll
                for (int fj = 0; fj < 4; ++fj)
                    acc[fi][fj] = __builtin_amdgcn_mfma_f32_16x16x32_bf16(
                        af[fi], bfr[fj], acc[fi][fj], 0, 0, 0);
        }
        asm volatile("s_waitcnt vmcnt(0)" ::: "memory");
        __syncthreads();
        cur ^= 1;
    }

    if (EPI == 0) {
        // bias + fast tanh-GELU -> bf16 Out. D row=(lane>>4)*4+reg, col=lane&15
        u16* O16 = (u16*)Out;
#pragma unroll
        for (int fi = 0; fi < 8; ++fi) {
#pragma unroll
            for (int fj = 0; fj < 4; ++fj) {
#pragma unroll
                for (int rr = 0; rr < 4; ++rr) {
                    int mrow = bm * 256 + wm * 128 + fi * 16 + lk * 4 + rr;
                    int ncol = bn * 256 + wn * 64 + fj * 16 + lr;
                    float v = acc[fi][fj][rr] + bias[ncol];
                    float u_ = v * (0.7978845608028654f + 0.03567740813636141f * v * v);
                    float ge = v / (1.f + __expf(-2.f * u_));
                    O16[(size_t)mrow * ND + ncol] = f2bf(ge);
                }
            }
        }
    } else {
        // two-phase (by wm): 128x256 f32 LDS C-tile (128 KB, exact smem reuse),
        // then WRITE-ONLY f32 out = bf16(xmid) + c  (dense float4 stores)
        float* Of = (float*)Out;
        float* Cs = (float*)smem;
#pragma unroll
        for (int half = 0; half < 2; ++half) {
            if (wm == half) {
#pragma unroll
                for (int fi = 0; fi < 8; ++fi) {
#pragma unroll
                    for (int fj = 0; fj < 4; ++fj) {
                        int col = wn * 64 + fj * 16 + lr;
                        float bcol = bias[bn * 256 + col];
#pragma unroll
                        for (int rr = 0; rr < 4; ++rr) {
                            int row = fi * 16 + lk * 4 + rr;   // 0..127
                            Cs[row * 256 + col] = acc[fi][fj][rr] + bcol;
                        }
                    }
                }
            }
            __syncthreads();
#pragma unroll
            for (int it = 0; it < 8; ++it) {
                int row = it * 16 + (tid >> 5);
                int cf = (tid & 31) * 8;
                float4 c0 = *(const float4*)(Cs + row * 256 + cf);
                float4 c1 = *(const float4*)(Cs + row * 256 + cf + 4);
                size_t go = (size_t)(row0 + bm * 256 + half * 128 + row) * ND
                            + bn * 256 + cf;
                uint4 xm = *(const uint4*)(Xm + go);
                const u16* xp = (const u16*)&xm;
                float4 r0, r1;
                r0.x = bf2f(xp[0]) + c0.x; r0.y = bf2f(xp[1]) + c0.y;
                r0.z = bf2f(xp[2]) + c0.z; r0.w = bf2f(xp[3]) + c0.w;
                r1.x = bf2f(xp[4]) + c1.x; r1.y = bf2f(xp[5]) + c1.y;
                r1.z = bf2f(xp[6]) + c1.z; r1.w = bf2f(xp[7]) + c1.w;
                *(float4*)(Of + go) = r0;
                *(float4*)(Of + go + 4) = r1;
            }
            __syncthreads();
        }
    }
}

// ---------------------------------------------------------------------------
extern "C" void kernel_launch(void* const* d_in, const int* in_sizes, int n_in,
                              void* d_out, int out_size, void* d_ws, size_t ws_size,
                              hipStream_t stream) {
    const float* x   = (const float*)d_in[0];
    const float* g1  = (const float*)d_in[1];
    const float* b1  = (const float*)d_in[2];
    const float* sw  = (const float*)d_in[3];
    const float* sb  = (const float*)d_in[4];
    const float* g2  = (const float*)d_in[5];
    const float* b2  = (const float*)d_in[6];
    const float* w1  = (const float*)d_in[7];
    const float* bb1 = (const float*)d_in[8];
    const float* w2  = (const float*)d_in[9];
    const float* bb2 = (const float*)d_in[10];
    float* out = (float*)d_out;

    char* ws = (char*)d_ws;
    u16* w1t = (u16*)ws;                                  // [2048][512]  2 MB
    u16* w2t = (u16*)(ws + 2097152);                      // [512][2048]  2 MB
    u16* swb = (u16*)(ws + 2u * 2097152);                 // [16][64][64] 128 KB
    size_t tok_bytes = (size_t)100352 * 512 * 2;          // 102.8 MB each
    u16* ln2c = (u16*)(ws + 2u * 2097152 + 131072);
    u16* xmid = (u16*)(ws + 2u * 2097152 + 131072 + tok_bytes);
    size_t hidoff = 2u * 2097152 + 131072 + 2u * tok_bytes;
    long avail = (long)ws_size - (long)hidoff;
    long maxT = avail / 524288;                           // hid per 128 rows
    int chunkT = (int)(maxT < 2 ? 2 : (maxT > 784 ? 784 : maxT));
    chunkT &= ~1;                                          // 256-row tiles
    u16* hid = (u16*)(ws + hidoff);

    transp_k<<<dim3(64, 16), 256, 0, stream>>>(w1, w1t, 512, 2048);
    transp_k<<<dim3(16, 64), 256, 0, stream>>>(w2, w2t, 2048, 512);
    swb_k<<<256, 256, 0, stream>>>(sw, swb);
    spatial_k<<<2592, 512, 0, stream>>>(x, g1, b1, swb, sb, g2, b2, xmid, ln2c);
    for (int t0 = 0; t0 < 784; t0 += chunkT) {
        int nt = (784 - t0) < chunkT ? (784 - t0) : chunkT;
        int nt2 = nt >> 1;                                 // 256-row tiles
        gemm_k<512, 2048, 0><<<nt2 * 8, 512, 0, stream>>>(
            ln2c + (size_t)t0 * 128 * 512, w1t, bb1, nullptr, hid, 0);
        gemm_k<2048, 512, 1><<<nt2 * 2, 512, 0, stream>>>(
            hid, w2t, bb2, xmid, out, t0 * 128);
    }
}

// Round 25
// 838.833 us; speedup vs baseline: 1.2061x; 1.0209x over previous
//
#include <hip/hip_runtime.h>
#include <cstdint>

using u16 = unsigned short;
using u32 = unsigned int;

typedef __bf16 bf16x8 __attribute__((ext_vector_type(8)));
typedef float f32x4 __attribute__((ext_vector_type(4)));

__device__ __forceinline__ float bf2f(u16 u) {
    u32 v = ((u32)u) << 16; float f; __builtin_memcpy(&f, &v, 4); return f;
}
__device__ __forceinline__ u16 f2bf(float f) {
    u32 u; __builtin_memcpy(&u, &f, 4);
    u32 r = (u + 0x7fffu + ((u >> 16) & 1u)) >> 16; return (u16)r;
}
__device__ __forceinline__ u32 pack2(float a, float b) {
    return (u32)f2bf(a) | ((u32)f2bf(b) << 16);
}
// bijective chunked XCD swizzle (m204)
__device__ __forceinline__ int xcd_swz(int orig, int nwg) {
    int q = nwg >> 3, r8 = nwg & 7;
    int xcd = orig & 7, slot = orig >> 3;
    return (xcd < r8 ? xcd * (q + 1) : r8 * (q + 1) + (xcd - r8) * q) + slot;
}
// async global->LDS, 16B/lane; LDS dest wave-uniform base + lane*16
__device__ __forceinline__ void async_cp16(const u16* g, u16* l) {
    __builtin_amdgcn_global_load_lds(
        (const __attribute__((address_space(1))) void*)g,
        (__attribute__((address_space(3))) void*)l, 16, 0, 0);
}

// ---------------------------------------------------------------------------
// weight transpose: w [R][C] fp32 -> wt [C][R] bf16
// ---------------------------------------------------------------------------
__global__ __launch_bounds__(256) void transp_k(const float* __restrict__ in,
                                                u16* __restrict__ outp,
                                                int R, int C) {
    __shared__ alignas(16) u16 t[32][33];
    int tx = threadIdx.x & 31, ty = threadIdx.x >> 5;
    int bx = blockIdx.x * 32, by = blockIdx.y * 32;
#pragma unroll
    for (int i = 0; i < 4; ++i)
        t[ty + i * 8][tx] = f2bf(in[(size_t)(by + ty + i * 8) * C + bx + tx]);
    __syncthreads();
#pragma unroll
    for (int i = 0; i < 4; ++i)
        outp[(size_t)(bx + ty + i * 8) * R + by + tx] = t[tx][ty + i * 8];
}

// ---------------------------------------------------------------------------
// swb prep: sw [16][49][49] f32 -> swb [16][64][64] bf16, zero-padded
// ---------------------------------------------------------------------------
__global__ __launch_bounds__(256) void swb_k(const float* __restrict__ sw,
                                             u16* __restrict__ swb) {
    int idx = blockIdx.x * 256 + threadIdx.x;       // 65536 total
    int h = idx >> 12, r = (idx >> 6) & 63, j = idx & 63;
    u16 v = 0;
    if (r < 49 && j < 49) v = f2bf(sw[(size_t)h * 2401 + r * 49 + j]);
    swb[idx] = v;
}

// ---------------------------------------------------------------------------
// Fused LN1 + MFMA window mix + LN2 (unchanged from round-24 pass)
// ---------------------------------------------------------------------------
__global__ __launch_bounds__(512) void spatial_k(const float* __restrict__ xin,
                                                 const float* __restrict__ g1,
                                                 const float* __restrict__ b1,
                                                 const u16* __restrict__ swb,
                                                 const float* __restrict__ sb,
                                                 const float* __restrict__ g2,
                                                 const float* __restrict__ b2,
                                                 u16* __restrict__ xmid,
                                                 u16* __restrict__ ln2o) {
    __shared__ alignas(16) char poolc[123904];       // raw(50176) | lnT(73728) ; oL union
    __shared__ float sbl[784];
    __shared__ int toks[49];
    u16* raw = (u16*)poolc;                          // [49][512] bf16
    u16* lnT = (u16*)(poolc + 50176);                // [512][72] bf16
    float* oL = (float*)poolc;                       // [49][520] f32 (after M)
    const int tid = threadIdx.x;
    const int wid = blockIdx.x;
    const int b = wid / 81, rem = wid % 81;
    const int wy = rem / 9, wx = rem % 9;

    if (tid < 49) {
        int py = tid / 7, px = tid % 7;
        int y = wy * 7 + py - 4, x = wx * 7 + px - 4;  // PT=PL=4
        toks[tid] = ((unsigned)y < 56u && (unsigned)x < 56u)
                        ? (b * 3136 + y * 56 + x) : -1;
    }
    for (int idx = tid; idx < 784; idx += 512) sbl[idx] = sb[idx];
    __syncthreads();

    const int l = tid & 63, wvi = tid >> 6;
    const int lr = l & 15, lk = l >> 4;

    // ---- phase A: LN1 per position (one wave per position, stride 8)
    {
        float g1v[8], b1v[8];
#pragma unroll
        for (int j = 0; j < 8; ++j) { g1v[j] = g1[l * 8 + j]; b1v[j] = b1[l * 8 + j]; }
        for (int p = wvi; p < 49; p += 8) {
            int tk = toks[p];
            uint4 w = make_uint4(0, 0, 0, 0);
            if (tk >= 0) {
                const float4* pp = (const float4*)(xin + (size_t)tk * 512 + l * 8);
                float4 a = pp[0], bb = pp[1];
                float v[8] = {a.x, a.y, a.z, a.w, bb.x, bb.y, bb.z, bb.w};
                float s = 0.f, qq = 0.f;
#pragma unroll
                for (int j = 0; j < 8; ++j) { s += v[j]; qq += v[j] * v[j]; }
#pragma unroll
                for (int off = 1; off < 64; off <<= 1) {
                    s += __shfl_xor(s, off); qq += __shfl_xor(qq, off);
                }
                float m = s * (1.f / 512.f);
                float var = qq * (1.f / 512.f) - m * m;
                float r = rsqrtf(var + 1e-5f);
                float o[8];
#pragma unroll
                for (int j = 0; j < 8; ++j)
                    o[j] = (v[j] - m) * r * g1v[j] + b1v[j];
                w.x = pack2(o[0], o[1]); w.y = pack2(o[2], o[3]);
                w.z = pack2(o[4], o[5]); w.w = pack2(o[6], o[7]);
            }
            *(uint4*)(raw + p * 512 + l * 8) = w;
        }
    }
    __syncthreads();

    // ---- phase T: transpose raw[j][c] -> lnT[c][j] (chunk-XOR, zero pad)
    {
        const int c = tid;
#pragma unroll
        for (int m = 0; m < 8; ++m) {
            u32 d[4];
#pragma unroll
            for (int e2 = 0; e2 < 4; ++e2) {
                int j0 = m * 8 + e2 * 2, j1 = j0 + 1;
                u16 v0 = (j0 < 49) ? raw[j0 * 512 + c] : (u16)0;
                u16 v1 = (j1 < 49) ? raw[j1 * 512 + c] : (u16)0;
                d[e2] = (u32)v0 | ((u32)v1 << 16);
            }
            uint4 w = make_uint4(d[0], d[1], d[2], d[3]);
            *(uint4*)(lnT + c * 72 + ((m ^ (c & 7)) * 8)) = w;
        }
    }
    __syncthreads();

    // ---- phase M: per wave heads {2*wvi, 2*wvi+1}; 16 MFMA per head
    f32x4 acc[2][4][2] = {};   // [hh][tp][tn]
#pragma unroll
    for (int hh = 0; hh < 2; ++hh) {
        const int h = wvi * 2 + hh;
        bf16x8 bfr[2][2];      // [tn][kk]
#pragma unroll
        for (int tn = 0; tn < 2; ++tn)
#pragma unroll
            for (int kk = 0; kk < 2; ++kk) {
                int crow = h * 32 + tn * 16 + lr;
                bfr[tn][kk] = *reinterpret_cast<const bf16x8*>(
                    lnT + crow * 72 + (((kk * 4 + lk) ^ (crow & 7)) * 8));
            }
        bf16x8 af[4][2];       // [tp][kk]
#pragma unroll
        for (int tp = 0; tp < 4; ++tp)
#pragma unroll
            for (int kk = 0; kk < 2; ++kk)
                af[tp][kk] = *reinterpret_cast<const bf16x8*>(
                    swb + h * 4096 + (tp * 16 + lr) * 64 + (kk * 4 + lk) * 8);
#pragma unroll
        for (int tp = 0; tp < 4; ++tp)
#pragma unroll
            for (int tn = 0; tn < 2; ++tn)
#pragma unroll
                for (int kk = 0; kk < 2; ++kk)
                    acc[hh][tp][tn] = __builtin_amdgcn_mfma_f32_16x16x32_bf16(
                        af[tp][kk], bfr[tn][kk], acc[hh][tp][tn], 0, 0, 0);
    }
    __syncthreads();   // all lnT reads retired before oL overwrites the union

    // ---- phase S: stage acc + sb into oL[p][520]
#pragma unroll
    for (int hh = 0; hh < 2; ++hh) {
        const int h = wvi * 2 + hh;
#pragma unroll
        for (int tp = 0; tp < 4; ++tp)
#pragma unroll
            for (int tn = 0; tn < 2; ++tn)
#pragma unroll
                for (int rg = 0; rg < 4; ++rg) {
                    int p = tp * 16 + lk * 4 + rg;
                    if (p < 49) {
                        int c = h * 32 + tn * 16 + lr;
                        oL[p * 520 + c] = acc[hh][tp][tn][rg] + sbl[h * 49 + p];
                    }
                }
    }
    __syncthreads();

    // ---- phase F: row-major finalize (one wave per position, stride 8)
    {
        float g2v[8], b2v[8];
#pragma unroll
        for (int j = 0; j < 8; ++j) { g2v[j] = g2[l * 8 + j]; b2v[j] = b2[l * 8 + j]; }
        for (int p = wvi; p < 49; p += 8) {
            int tk = toks[p];
            if (tk < 0) continue;
            const float* orow = oL + p * 520 + l * 8;
            float4 oa = *(const float4*)orow;
            float4 ob = *(const float4*)(orow + 4);
            const float4* xp4 = (const float4*)(xin + (size_t)tk * 512 + l * 8);
            float4 xa = xp4[0], xb = xp4[1];
            float o[8] = {oa.x + xa.x, oa.y + xa.y, oa.z + xa.z, oa.w + xa.w,
                          ob.x + xb.x, ob.y + xb.y, ob.z + xb.z, ob.w + xb.w};
            float s = 0.f, qq = 0.f;
#pragma unroll
            for (int j = 0; j < 8; ++j) { s += o[j]; qq += o[j] * o[j]; }
#pragma unroll
            for (int off = 1; off < 64; off <<= 1) {
                s += __shfl_xor(s, off); qq += __shfl_xor(qq, off);
            }
            float m = s * (1.f / 512.f);
            float var = qq * (1.f / 512.f) - m * m;
            float r = rsqrtf(var + 1e-5f);
            uint4 wx_, wl_;
            wx_.x = pack2(o[0], o[1]); wx_.y = pack2(o[2], o[3]);
            wx_.z = pack2(o[4], o[5]); wx_.w = pack2(o[6], o[7]);
            float ln[8];
#pragma unroll
            for (int j = 0; j < 8; ++j)
                ln[j] = (o[j] - m) * r * g2v[j] + b2v[j];
            wl_.x = pack2(ln[0], ln[1]); wl_.y = pack2(ln[2], ln[3]);
            wl_.z = pack2(ln[4], ln[5]); wl_.w = pack2(ln[6], ln[7]);
            *(uint4*)(xmid + (size_t)tk * 512 + l * 8) = wx_;
            *(uint4*)(ln2o + (size_t)tk * 512 + l * 8) = wl_;
        }
    }
}

// ---------------------------------------------------------------------------
// MFMA GEMM, SINGLE-barrier-per-K-step variant of the R12 structure:
// 256x256 tile, 8 waves (2m x 4n), BK=64, 2-slot dbuf (128 KB), gload_lds.
// Per K-step: vmcnt(0) [drains ONLY tile ks's loads — tile ks+1's are not
// yet issued] -> barrier [publishes all waves' tile-ks loads; also proves
// every wave consumed its buf^1 ds_reads from step ks-1, so staging into
// buf^1 below is safe] -> stage(ks+1 -> buf^1) [flies across the MFMA
// block] -> 64 MFMA (setprio). Halves the rendezvous count vs R12.
// EPI==0: bias + fast tanh-GELU -> Out bf16 (chunk-local rows)
// EPI==1: two-phase (by wm) 128x256 f32 LDS C-tile + WRITE-ONLY f32 out:
//         out = bf16(xmid) + (acc+bias)
// ---------------------------------------------------------------------------
template <int KD, int ND, int EPI>
__global__ __launch_bounds__(512) void gemm_k(const u16* __restrict__ A,
                                              const u16* __restrict__ Wt,
                                              const float* __restrict__ bias,
                                              const u16* __restrict__ Xm,
                                              void* __restrict__ Out, int row0) {
    __shared__ alignas(16) u16 smem[2 * 32768];   // [buf][A(16K u16)|B(16K u16)]
    const int tid = threadIdx.x;
    const int l = tid & 63, wid = tid >> 6;
    const int wm = wid >> 2, wn = wid & 3;
    const int lr = l & 15, lk = l >> 4;

    const int wg = xcd_swz(blockIdx.x, gridDim.x);
    constexpr int NTN = ND / 256;
    const int bm = wg / NTN, bn = wg % NTN;   // consecutive wg share bm

    // staging: physical slot s holds logical chunk pc^(rr&7); 4 A + 4 B per thread
    const u16* gA[4]; const u16* gB[4];
    int lofs[4];
#pragma unroll
    for (int i = 0; i < 4; ++i) {
        int s = (wid * 4 + i) * 64 + l;            // [0, 2048)
        int rr = s >> 3, pc = s & 7, cc = pc ^ (rr & 7);
        gA[i] = A  + (size_t)(bm * 256 + rr) * KD + cc * 8;
        gB[i] = Wt + (size_t)(bn * 256 + rr) * KD + cc * 8;
        lofs[i] = (wid * 4 + i) * 512;             // element offset, wave-uniform
    }

    f32x4 acc[8][4] = {};

    // prologue: stage tile 0 into buf 0
#pragma unroll
    for (int i = 0; i < 4; ++i) async_cp16(gA[i], smem + lofs[i]);
#pragma unroll
    for (int i = 0; i < 4; ++i) async_cp16(gB[i], smem + 16384 + lofs[i]);
#pragma unroll
    for (int i = 0; i < 4; ++i) { gA[i] += 64; gB[i] += 64; }

    int cur = 0;
    for (int ks = 0; ks < KD; ks += 64) {
        // drain tile ks's loads (the only outstanding ones), publish to block
        asm volatile("s_waitcnt vmcnt(0)" ::: "memory");
        __builtin_amdgcn_s_barrier();
        // stage tile ks+1 into the other buffer; flies across the MFMA block
        if (ks + 64 < KD) {
            u16* dst = smem + (cur ^ 1) * 32768;
#pragma unroll
            for (int i = 0; i < 4; ++i) async_cp16(gA[i], dst + lofs[i]);
#pragma unroll
            for (int i = 0; i < 4; ++i) async_cp16(gB[i], dst + 16384 + lofs[i]);
#pragma unroll
            for (int i = 0; i < 4; ++i) { gA[i] += 64; gB[i] += 64; }
        }
        const u16* As = smem + cur * 32768;
        const u16* Bs = As + 16384;
#pragma unroll
        for (int kk = 0; kk < 2; ++kk) {
            bf16x8 af[8], bfr[4];
#pragma unroll
            for (int f = 0; f < 8; ++f) {
                int ra = wm * 128 + f * 16 + lr;
                af[f] = *reinterpret_cast<const bf16x8*>(
                    As + ra * 64 + (((kk * 4 + lk) ^ (ra & 7)) * 8));
            }
#pragma unroll
            for (int f = 0; f < 4; ++f) {
                int rb = wn * 64 + f * 16 + lr;
                bfr[f] = *reinterpret_cast<const bf16x8*>(
                    Bs + rb * 64 + (((kk * 4 + lk) ^ (rb & 7)) * 8));
            }
            __builtin_amdgcn_s_setprio(1);
#pragma unroll
            for (int fi = 0; fi < 8; ++fi)
#pragma unroll
                for (int fj = 0; fj < 4; ++fj)
                    acc[fi][fj] = __builtin_amdgcn_mfma_f32_16x16x32_bf16(
                        af[fi], bfr[fj], acc[fi][fj], 0, 0, 0);
            __builtin_amdgcn_s_setprio(0);
        }
        cur ^= 1;
    }
    __syncthreads();   // retire all waves' LDS reads before epilogue smem reuse

    if (EPI == 0) {
        // bias + fast tanh-GELU -> bf16 Out. D row=(lane>>4)*4+reg, col=lane&15
        u16* O16 = (u16*)Out;
#pragma unroll
        for (int fi = 0; fi < 8; ++fi) {
#pragma unroll
            for (int fj = 0; fj < 4; ++fj) {
#pragma unroll
                for (int rr = 0; rr < 4; ++rr) {
                    int mrow = bm * 256 + wm * 128 + fi * 16 + lk * 4 + rr;
                    int ncol = bn * 256 + wn * 64 + fj * 16 + lr;
                    float v = acc[fi][fj][rr] + bias[ncol];
                    float u_ = v * (0.7978845608028654f + 0.03567740813636141f * v * v);
                    float ge = v / (1.f + __expf(-2.f * u_));
                    O16[(size_t)mrow * ND + ncol] = f2bf(ge);
                }
            }
        }
    } else {
        // two-phase (by wm): 128x256 f32 LDS C-tile (128 KB, exact smem reuse),
        // then WRITE-ONLY f32 out = bf16(xmid) + c  (dense float4 stores)
        float* Of = (float*)Out;
        float* Cs = (float*)smem;
#pragma unroll
        for (int half = 0; half < 2; ++half) {
            if (wm == half) {
#pragma unroll
                for (int fi = 0; fi < 8; ++fi) {
#pragma unroll
                    for (int fj = 0; fj < 4; ++fj) {
                        int col = wn * 64 + fj * 16 + lr;
                        float bcol = bias[bn * 256 + col];
#pragma unroll
                        for (int rr = 0; rr < 4; ++rr) {
                            int row = fi * 16 + lk * 4 + rr;   // 0..127
                            Cs[row * 256 + col] = acc[fi][fj][rr] + bcol;
                        }
                    }
                }
            }
            __syncthreads();
#pragma unroll
            for (int it = 0; it < 8; ++it) {
                int row = it * 16 + (tid >> 5);
                int cf = (tid & 31) * 8;
                float4 c0 = *(const float4*)(Cs + row * 256 + cf);
                float4 c1 = *(const float4*)(Cs + row * 256 + cf + 4);
                size_t go = (size_t)(row0 + bm * 256 + half * 128 + row) * ND
                            + bn * 256 + cf;
                uint4 xm = *(const uint4*)(Xm + go);
                const u16* xp = (const u16*)&xm;
                float4 r0, r1;
                r0.x = bf2f(xp[0]) + c0.x; r0.y = bf2f(xp[1]) + c0.y;
                r0.z = bf2f(xp[2]) + c0.z; r0.w = bf2f(xp[3]) + c0.w;
                r1.x = bf2f(xp[4]) + c1.x; r1.y = bf2f(xp[5]) + c1.y;
                r1.z = bf2f(xp[6]) + c1.z; r1.w = bf2f(xp[7]) + c1.w;
                *(float4*)(Of + go) = r0;
                *(float4*)(Of + go + 4) = r1;
            }
            __syncthreads();
        }
    }
}

// ---------------------------------------------------------------------------
extern "C" void kernel_launch(void* const* d_in, const int* in_sizes, int n_in,
                              void* d_out, int out_size, void* d_ws, size_t ws_size,
                              hipStream_t stream) {
    const float* x   = (const float*)d_in[0];
    const float* g1  = (const float*)d_in[1];
    const float* b1  = (const float*)d_in[2];
    const float* sw  = (const float*)d_in[3];
    const float* sb  = (const float*)d_in[4];
    const float* g2  = (const float*)d_in[5];
    const float* b2  = (const float*)d_in[6];
    const float* w1  = (const float*)d_in[7];
    const float* bb1 = (const float*)d_in[8];
    const float* w2  = (const float*)d_in[9];
    const float* bb2 = (const float*)d_in[10];
    float* out = (float*)d_out;

    char* ws = (char*)d_ws;
    u16* w1t = (u16*)ws;                                  // [2048][512]  2 MB
    u16* w2t = (u16*)(ws + 2097152);                      // [512][2048]  2 MB
    u16* swb = (u16*)(ws + 2u * 2097152);                 // [16][64][64] 128 KB
    size_t tok_bytes = (size_t)100352 * 512 * 2;          // 102.8 MB each
    u16* ln2c = (u16*)(ws + 2u * 2097152 + 131072);
    u16* xmid = (u16*)(ws + 2u * 2097152 + 131072 + tok_bytes);
    size_t hidoff = 2u * 2097152 + 131072 + 2u * tok_bytes;
    long avail = (long)ws_size - (long)hidoff;
    long maxT = avail / 524288;                           // hid per 128 rows
    int chunkT = (int)(maxT < 2 ? 2 : (maxT > 784 ? 784 : maxT));
    chunkT &= ~1;                                          // 256-row tiles
    u16* hid = (u16*)(ws + hidoff);

    transp_k<<<dim3(64, 16), 256, 0, stream>>>(w1, w1t, 512, 2048);
    transp_k<<<dim3(16, 64), 256, 0, stream>>>(w2, w2t, 2048, 512);
    swb_k<<<256, 256, 0, stream>>>(sw, swb);
    spatial_k<<<2592, 512, 0, stream>>>(x, g1, b1, swb, sb, g2, b2, xmid, ln2c);
    for (int t0 = 0; t0 < 784; t0 += chunkT) {
        int nt = (784 - t0) < chunkT ? (784 - t0) : chunkT;
        int nt2 = nt >> 1;                                 // 256-row tiles
        gemm_k<512, 2048, 0><<<nt2 * 8, 512, 0, stream>>>(
            ln2c + (size_t)t0 * 128 * 512, w1t, bb1, nullptr, hid, 0);
        gemm_k<2048, 512, 1><<<nt2 * 2, 512, 0, stream>>>(
            hid, w2t, bb2, xmid, out, t0 * 128);
    }
}

// Round 26
// 819.010 us; speedup vs baseline: 1.2353x; 1.0242x over previous
//
#include <hip/hip_runtime.h>
#include <cstdint>

using u16 = unsigned short;
using u32 = unsigned int;

typedef __bf16 bf16x8 __attribute__((ext_vector_type(8)));
typedef float f32x4 __attribute__((ext_vector_type(4)));

__device__ __forceinline__ float bf2f(u16 u) {
    u32 v = ((u32)u) << 16; float f; __builtin_memcpy(&f, &v, 4); return f;
}
__device__ __forceinline__ u16 f2bf(float f) {
    u32 u; __builtin_memcpy(&u, &f, 4);
    u32 r = (u + 0x7fffu + ((u >> 16) & 1u)) >> 16; return (u16)r;
}
__device__ __forceinline__ u32 pack2(float a, float b) {
    return (u32)f2bf(a) | ((u32)f2bf(b) << 16);
}
// bijective chunked XCD swizzle (m204)
__device__ __forceinline__ int xcd_swz(int orig, int nwg) {
    int q = nwg >> 3, r8 = nwg & 7;
    int xcd = orig & 7, slot = orig >> 3;
    return (xcd < r8 ? xcd * (q + 1) : r8 * (q + 1) + (xcd - r8) * q) + slot;
}
// async global->LDS, 16B/lane; LDS dest wave-uniform base + lane*16
__device__ __forceinline__ void async_cp16(const u16* g, u16* l) {
    __builtin_amdgcn_global_load_lds(
        (const __attribute__((address_space(1))) void*)g,
        (__attribute__((address_space(3))) void*)l, 16, 0, 0);
}

// ---------------------------------------------------------------------------
// weight transpose: w [R][C] fp32 -> wt [C][R] bf16
// ---------------------------------------------------------------------------
__global__ __launch_bounds__(256) void transp_k(const float* __restrict__ in,
                                                u16* __restrict__ outp,
                                                int R, int C) {
    __shared__ alignas(16) u16 t[32][33];
    int tx = threadIdx.x & 31, ty = threadIdx.x >> 5;
    int bx = blockIdx.x * 32, by = blockIdx.y * 32;
#pragma unroll
    for (int i = 0; i < 4; ++i)
        t[ty + i * 8][tx] = f2bf(in[(size_t)(by + ty + i * 8) * C + bx + tx]);
    __syncthreads();
#pragma unroll
    for (int i = 0; i < 4; ++i)
        outp[(size_t)(bx + ty + i * 8) * R + by + tx] = t[tx][ty + i * 8];
}

// ---------------------------------------------------------------------------
// swb prep: sw [16][49][49] f32 -> swb [16][64][64] bf16, zero-padded
// ---------------------------------------------------------------------------
__global__ __launch_bounds__(256) void swb_k(const float* __restrict__ sw,
                                             u16* __restrict__ swb) {
    int idx = blockIdx.x * 256 + threadIdx.x;       // 65536 total
    int h = idx >> 12, r = (idx >> 6) & 63, j = idx & 63;
    u16 v = 0;
    if (r < 49 && j < 49) v = f2bf(sw[(size_t)h * 2401 + r * 49 + j]);
    swb[idx] = v;
}

// ---------------------------------------------------------------------------
// Fused LN1 + MFMA window mix + LN2.
//   A: LN1 -> raw[j][c] bf16 (zeros at pads); x rows CACHED in registers
//   T: transpose raw -> lnT[c][72] (chunk-XOR m^(c&7), K-pad 64)
//   M: per wave 2 heads; OUT_h = SW_h @ LN_h via 16x16x32 MFMA
//   S: stage acc+sb -> oL[49][520] f32 (LDS union over raw+lnT)
//   F: row-major finalize using cached x (no 2nd HBM read of x):
//      o = oL + xr, 64-lane LN2 reduce, packed uint4 writes
// ---------------------------------------------------------------------------
__global__ __launch_bounds__(512) void spatial_k(const float* __restrict__ xin,
                                                 const float* __restrict__ g1,
                                                 const float* __restrict__ b1,
                                                 const u16* __restrict__ swb,
                                                 const float* __restrict__ sb,
                                                 const float* __restrict__ g2,
                                                 const float* __restrict__ b2,
                                                 u16* __restrict__ xmid,
                                                 u16* __restrict__ ln2o) {
    __shared__ alignas(16) char poolc[123904];       // raw(50176) | lnT(73728) ; oL union
    __shared__ float sbl[784];
    __shared__ int toks[49];
    u16* raw = (u16*)poolc;                          // [49][512] bf16
    u16* lnT = (u16*)(poolc + 50176);                // [512][72] bf16
    float* oL = (float*)poolc;                       // [49][520] f32 (after M)
    const int tid = threadIdx.x;
    const int wid = blockIdx.x;
    const int b = wid / 81, rem = wid % 81;
    const int wy = rem / 9, wx = rem % 9;

    if (tid < 49) {
        int py = tid / 7, px = tid % 7;
        int y = wy * 7 + py - 4, x = wx * 7 + px - 4;  // PT=PL=4
        toks[tid] = ((unsigned)y < 56u && (unsigned)x < 56u)
                        ? (b * 3136 + y * 56 + x) : -1;
    }
    for (int idx = tid; idx < 784; idx += 512) sbl[idx] = sb[idx];
    __syncthreads();

    const int l = tid & 63, wvi = tid >> 6;
    const int lr = l & 15, lk = l >> 4;

    float xr[7][8];   // cached x rows for this thread's positions (A -> F)

    // ---- phase A: LN1 per position (one wave per position, stride 8)
    {
        float g1v[8], b1v[8];
#pragma unroll
        for (int j = 0; j < 8; ++j) { g1v[j] = g1[l * 8 + j]; b1v[j] = b1[l * 8 + j]; }
#pragma unroll
        for (int it = 0; it < 7; ++it) {
            int p = wvi + it * 8;
            if (p < 49) {
                int tk = toks[p];
                uint4 w = make_uint4(0, 0, 0, 0);
                if (tk >= 0) {
                    const float4* pp = (const float4*)(xin + (size_t)tk * 512 + l * 8);
                    float4 a = pp[0], bb = pp[1];
                    float v[8] = {a.x, a.y, a.z, a.w, bb.x, bb.y, bb.z, bb.w};
#pragma unroll
                    for (int j = 0; j < 8; ++j) xr[it][j] = v[j];
                    float s = 0.f, qq = 0.f;
#pragma unroll
                    for (int j = 0; j < 8; ++j) { s += v[j]; qq += v[j] * v[j]; }
#pragma unroll
                    for (int off = 1; off < 64; off <<= 1) {
                        s += __shfl_xor(s, off); qq += __shfl_xor(qq, off);
                    }
                    float m = s * (1.f / 512.f);
                    float var = qq * (1.f / 512.f) - m * m;
                    float r = rsqrtf(var + 1e-5f);
                    float o[8];
#pragma unroll
                    for (int j = 0; j < 8; ++j)
                        o[j] = (v[j] - m) * r * g1v[j] + b1v[j];
                    w.x = pack2(o[0], o[1]); w.y = pack2(o[2], o[3]);
                    w.z = pack2(o[4], o[5]); w.w = pack2(o[6], o[7]);
                }
                *(uint4*)(raw + p * 512 + l * 8) = w;
            }
        }
    }
    __syncthreads();

    // ---- phase T: transpose raw[j][c] -> lnT[c][j] (chunk-XOR, zero pad)
    {
        const int c = tid;
#pragma unroll
        for (int m = 0; m < 8; ++m) {
            u32 d[4];
#pragma unroll
            for (int e2 = 0; e2 < 4; ++e2) {
                int j0 = m * 8 + e2 * 2, j1 = j0 + 1;
                u16 v0 = (j0 < 49) ? raw[j0 * 512 + c] : (u16)0;
                u16 v1 = (j1 < 49) ? raw[j1 * 512 + c] : (u16)0;
                d[e2] = (u32)v0 | ((u32)v1 << 16);
            }
            uint4 w = make_uint4(d[0], d[1], d[2], d[3]);
            *(uint4*)(lnT + c * 72 + ((m ^ (c & 7)) * 8)) = w;
        }
    }
    __syncthreads();

    // ---- phase M: per wave heads {2*wvi, 2*wvi+1}; 16 MFMA per head
    f32x4 acc[2][4][2] = {};   // [hh][tp][tn]
#pragma unroll
    for (int hh = 0; hh < 2; ++hh) {
        const int h = wvi * 2 + hh;
        bf16x8 bfr[2][2];      // [tn][kk]
#pragma unroll
        for (int tn = 0; tn < 2; ++tn)
#pragma unroll
            for (int kk = 0; kk < 2; ++kk) {
                int crow = h * 32 + tn * 16 + lr;
                bfr[tn][kk] = *reinterpret_cast<const bf16x8*>(
                    lnT + crow * 72 + (((kk * 4 + lk) ^ (crow & 7)) * 8));
            }
        bf16x8 af[4][2];       // [tp][kk]
#pragma unroll
        for (int tp = 0; tp < 4; ++tp)
#pragma unroll
            for (int kk = 0; kk < 2; ++kk)
                af[tp][kk] = *reinterpret_cast<const bf16x8*>(
                    swb + h * 4096 + (tp * 16 + lr) * 64 + (kk * 4 + lk) * 8);
#pragma unroll
        for (int tp = 0; tp < 4; ++tp)
#pragma unroll
            for (int tn = 0; tn < 2; ++tn)
#pragma unroll
                for (int kk = 0; kk < 2; ++kk)
                    acc[hh][tp][tn] = __builtin_amdgcn_mfma_f32_16x16x32_bf16(
                        af[tp][kk], bfr[tn][kk], acc[hh][tp][tn], 0, 0, 0);
    }
    __syncthreads();   // all lnT reads retired before oL overwrites the union

    // ---- phase S: stage acc + sb into oL[p][520]
#pragma unroll
    for (int hh = 0; hh < 2; ++hh) {
        const int h = wvi * 2 + hh;
#pragma unroll
        for (int tp = 0; tp < 4; ++tp)
#pragma unroll
            for (int tn = 0; tn < 2; ++tn)
#pragma unroll
                for (int rg = 0; rg < 4; ++rg) {
                    int p = tp * 16 + lk * 4 + rg;
                    if (p < 49) {
                        int c = h * 32 + tn * 16 + lr;
                        oL[p * 520 + c] = acc[hh][tp][tn][rg] + sbl[h * 49 + p];
                    }
                }
    }
    __syncthreads();

    // ---- phase F: row-major finalize (cached x, one wave per position)
    {
        float g2v[8], b2v[8];
#pragma unroll
        for (int j = 0; j < 8; ++j) { g2v[j] = g2[l * 8 + j]; b2v[j] = b2[l * 8 + j]; }
#pragma unroll
        for (int it = 0; it < 7; ++it) {
            int p = wvi + it * 8;
            if (p < 49) {
                int tk = toks[p];
                if (tk >= 0) {
                    const float* orow = oL + p * 520 + l * 8;
                    float4 oa = *(const float4*)orow;
                    float4 ob = *(const float4*)(orow + 4);
                    float o[8] = {oa.x + xr[it][0], oa.y + xr[it][1],
                                  oa.z + xr[it][2], oa.w + xr[it][3],
                                  ob.x + xr[it][4], ob.y + xr[it][5],
                                  ob.z + xr[it][6], ob.w + xr[it][7]};
                    float s = 0.f, qq = 0.f;
#pragma unroll
                    for (int j = 0; j < 8; ++j) { s += o[j]; qq += o[j] * o[j]; }
#pragma unroll
                    for (int off = 1; off < 64; off <<= 1) {
                        s += __shfl_xor(s, off); qq += __shfl_xor(qq, off);
                    }
                    float m = s * (1.f / 512.f);
                    float var = qq * (1.f / 512.f) - m * m;
                    float r = rsqrtf(var + 1e-5f);
                    uint4 wx_, wl_;
                    wx_.x = pack2(o[0], o[1]); wx_.y = pack2(o[2], o[3]);
                    wx_.z = pack2(o[4], o[5]); wx_.w = pack2(o[6], o[7]);
                    float ln[8];
#pragma unroll
                    for (int j = 0; j < 8; ++j)
                        ln[j] = (o[j] - m) * r * g2v[j] + b2v[j];
                    wl_.x = pack2(ln[0], ln[1]); wl_.y = pack2(ln[2], ln[3]);
                    wl_.z = pack2(ln[4], ln[5]); wl_.w = pack2(ln[6], ln[7]);
                    *(uint4*)(xmid + (size_t)tk * 512 + l * 8) = wx_;
                    *(uint4*)(ln2o + (size_t)tk * 512 + l * 8) = wl_;
                }
            }
        }
    }
}

// ---------------------------------------------------------------------------
// MFMA GEMM, SINGLE-barrier-per-K-step (round-25 measured variant):
// 256x256 tile, 8 waves (2m x 4n), BK=64, 2-slot dbuf (128 KB), gload_lds.
// Per K-step: vmcnt(0) -> barrier -> stage(ks+1 -> buf^1) -> 64 MFMA
// (setprio). XCD-swizzled 1D grid.
// EPI==0: bias + fast tanh-GELU -> Out bf16 (chunk-local rows)
// EPI==1: two-phase (by wm) 128x256 f32 LDS C-tile + WRITE-ONLY f32 out:
//         out = bf16(xmid) + (acc+bias)
// ---------------------------------------------------------------------------
template <int KD, int ND, int EPI>
__global__ __launch_bounds__(512) void gemm_k(const u16* __restrict__ A,
                                              const u16* __restrict__ Wt,
                                              const float* __restrict__ bias,
                                              const u16* __restrict__ Xm,
                                              void* __restrict__ Out, int row0) {
    __shared__ alignas(16) u16 smem[2 * 32768];   // [buf][A(16K u16)|B(16K u16)]
    const int tid = threadIdx.x;
    const int l = tid & 63, wid = tid >> 6;
    const int wm = wid >> 2, wn = wid & 3;
    const int lr = l & 15, lk = l >> 4;

    const int wg = xcd_swz(blockIdx.x, gridDim.x);
    constexpr int NTN = ND / 256;
    const int bm = wg / NTN, bn = wg % NTN;   // consecutive wg share bm

    // staging: physical slot s holds logical chunk pc^(rr&7); 4 A + 4 B per thread
    const u16* gA[4]; const u16* gB[4];
    int lofs[4];
#pragma unroll
    for (int i = 0; i < 4; ++i) {
        int s = (wid * 4 + i) * 64 + l;            // [0, 2048)
        int rr = s >> 3, pc = s & 7, cc = pc ^ (rr & 7);
        gA[i] = A  + (size_t)(bm * 256 + rr) * KD + cc * 8;
        gB[i] = Wt + (size_t)(bn * 256 + rr) * KD + cc * 8;
        lofs[i] = (wid * 4 + i) * 512;             // element offset, wave-uniform
    }

    f32x4 acc[8][4] = {};

    // prologue: stage tile 0 into buf 0
#pragma unroll
    for (int i = 0; i < 4; ++i) async_cp16(gA[i], smem + lofs[i]);
#pragma unroll
    for (int i = 0; i < 4; ++i) async_cp16(gB[i], smem + 16384 + lofs[i]);
#pragma unroll
    for (int i = 0; i < 4; ++i) { gA[i] += 64; gB[i] += 64; }

    int cur = 0;
    for (int ks = 0; ks < KD; ks += 64) {
        // drain tile ks's loads (the only outstanding ones), publish to block
        asm volatile("s_waitcnt vmcnt(0)" ::: "memory");
        __builtin_amdgcn_s_barrier();
        // stage tile ks+1 into the other buffer; flies across the MFMA block
        if (ks + 64 < KD) {
            u16* dst = smem + (cur ^ 1) * 32768;
#pragma unroll
            for (int i = 0; i < 4; ++i) async_cp16(gA[i], dst + lofs[i]);
#pragma unroll
            for (int i = 0; i < 4; ++i) async_cp16(gB[i], dst + 16384 + lofs[i]);
#pragma unroll
            for (int i = 0; i < 4; ++i) { gA[i] += 64; gB[i] += 64; }
        }
        const u16* As = smem + cur * 32768;
        const u16* Bs = As + 16384;
#pragma unroll
        for (int kk = 0; kk < 2; ++kk) {
            bf16x8 af[8], bfr[4];
#pragma unroll
            for (int f = 0; f < 8; ++f) {
                int ra = wm * 128 + f * 16 + lr;
                af[f] = *reinterpret_cast<const bf16x8*>(
                    As + ra * 64 + (((kk * 4 + lk) ^ (ra & 7)) * 8));
            }
#pragma unroll
            for (int f = 0; f < 4; ++f) {
                int rb = wn * 64 + f * 16 + lr;
                bfr[f] = *reinterpret_cast<const bf16x8*>(
                    Bs + rb * 64 + (((kk * 4 + lk) ^ (rb & 7)) * 8));
            }
            __builtin_amdgcn_s_setprio(1);
#pragma unroll
            for (int fi = 0; fi < 8; ++fi)
#pragma unroll
                for (int fj = 0; fj < 4; ++fj)
                    acc[fi][fj] = __builtin_amdgcn_mfma_f32_16x16x32_bf16(
                        af[fi], bfr[fj], acc[fi][fj], 0, 0, 0);
            __builtin_amdgcn_s_setprio(0);
        }
        cur ^= 1;
    }
    __syncthreads();   // retire all waves' LDS reads before epilogue smem reuse

    if (EPI == 0) {
        // bias + fast tanh-GELU -> bf16 Out. D row=(lane>>4)*4+reg, col=lane&15
        u16* O16 = (u16*)Out;
#pragma unroll
        for (int fi = 0; fi < 8; ++fi) {
#pragma unroll
            for (int fj = 0; fj < 4; ++fj) {
#pragma unroll
                for (int rr = 0; rr < 4; ++rr) {
                    int mrow = bm * 256 + wm * 128 + fi * 16 + lk * 4 + rr;
                    int ncol = bn * 256 + wn * 64 + fj * 16 + lr;
                    float v = acc[fi][fj][rr] + bias[ncol];
                    float u_ = v * (0.7978845608028654f + 0.03567740813636141f * v * v);
                    float ge = v / (1.f + __expf(-2.f * u_));
                    O16[(size_t)mrow * ND + ncol] = f2bf(ge);
                }
            }
        }
    } else {
        // two-phase (by wm): 128x256 f32 LDS C-tile (128 KB, exact smem reuse),
        // then WRITE-ONLY f32 out = bf16(xmid) + c  (dense float4 stores)
        float* Of = (float*)Out;
        float* Cs = (float*)smem;
#pragma unroll
        for (int half = 0; half < 2; ++half) {
            if (wm == half) {
#pragma unroll
                for (int fi = 0; fi < 8; ++fi) {
#pragma unroll
                    for (int fj = 0; fj < 4; ++fj) {
                        int col = wn * 64 + fj * 16 + lr;
                        float bcol = bias[bn * 256 + col];
#pragma unroll
                        for (int rr = 0; rr < 4; ++rr) {
                            int row = fi * 16 + lk * 4 + rr;   // 0..127
                            Cs[row * 256 + col] = acc[fi][fj][rr] + bcol;
                        }
                    }
                }
            }
            __syncthreads();
#pragma unroll
            for (int it = 0; it < 8; ++it) {
                int row = it * 16 + (tid >> 5);
                int cf = (tid & 31) * 8;
                float4 c0 = *(const float4*)(Cs + row * 256 + cf);
                float4 c1 = *(const float4*)(Cs + row * 256 + cf + 4);
                size_t go = (size_t)(row0 + bm * 256 + half * 128 + row) * ND
                            + bn * 256 + cf;
                uint4 xm = *(const uint4*)(Xm + go);
                const u16* xp = (const u16*)&xm;
                float4 r0, r1;
                r0.x = bf2f(xp[0]) + c0.x; r0.y = bf2f(xp[1]) + c0.y;
                r0.z = bf2f(xp[2]) + c0.z; r0.w = bf2f(xp[3]) + c0.w;
                r1.x = bf2f(xp[4]) + c1.x; r1.y = bf2f(xp[5]) + c1.y;
                r1.z = bf2f(xp[6]) + c1.z; r1.w = bf2f(xp[7]) + c1.w;
                *(float4*)(Of + go) = r0;
                *(float4*)(Of + go + 4) = r1;
            }
            __syncthreads();
        }
    }
}

// ---------------------------------------------------------------------------
extern "C" void kernel_launch(void* const* d_in, const int* in_sizes, int n_in,
                              void* d_out, int out_size, void* d_ws, size_t ws_size,
                              hipStream_t stream) {
    const float* x   = (const float*)d_in[0];
    const float* g1  = (const float*)d_in[1];
    const float* b1  = (const float*)d_in[2];
    const float* sw  = (const float*)d_in[3];
    const float* sb  = (const float*)d_in[4];
    const float* g2  = (const float*)d_in[5];
    const float* b2  = (const float*)d_in[6];
    const float* w1  = (const float*)d_in[7];
    const float* bb1 = (const float*)d_in[8];
    const float* w2  = (const float*)d_in[9];
    const float* bb2 = (const float*)d_in[10];
    float* out = (float*)d_out;

    char* ws = (char*)d_ws;
    u16* w1t = (u16*)ws;                                  // [2048][512]  2 MB
    u16* w2t = (u16*)(ws + 2097152);                      // [512][2048]  2 MB
    u16* swb = (u16*)(ws + 2u * 2097152);                 // [16][64][64] 128 KB
    size_t tok_bytes = (size_t)100352 * 512 * 2;          // 102.8 MB each
    u16* ln2c = (u16*)(ws + 2u * 2097152 + 131072);
    u16* xmid = (u16*)(ws + 2u * 2097152 + 131072 + tok_bytes);
    size_t hidoff = 2u * 2097152 + 131072 + 2u * tok_bytes;
    long avail = (long)ws_size - (long)hidoff;
    long maxT = avail / 524288;                           // hid per 128 rows
    int chunkT = (int)(maxT < 2 ? 2 : (maxT > 784 ? 784 : maxT));
    chunkT &= ~1;                                          // 256-row tiles
    u16* hid = (u16*)(ws + hidoff);

    transp_k<<<dim3(64, 16), 256, 0, stream>>>(w1, w1t, 512, 2048);
    transp_k<<<dim3(16, 64), 256, 0, stream>>>(w2, w2t, 2048, 512);
    swb_k<<<256, 256, 0, stream>>>(sw, swb);
    spatial_k<<<2592, 512, 0, stream>>>(x, g1, b1, swb, sb, g2, b2, xmid, ln2c);
    for (int t0 = 0; t0 < 784; t0 += chunkT) {
        int nt = (784 - t0) < chunkT ? (784 - t0) : chunkT;
        int nt2 = nt >> 1;                                 // 256-row tiles
        gemm_k<512, 2048, 0><<<nt2 * 8, 512, 0, stream>>>(
            ln2c + (size_t)t0 * 128 * 512, w1t, bb1, nullptr, hid, 0);
        gemm_k<2048, 512, 1><<<nt2 * 2, 512, 0, stream>>>(
            hid, w2t, bb2, xmid, out, t0 * 128);
    }
}